// Round 1
// baseline (1048.590 us; speedup 1.0000x reference)
//
#include <hip/hip_runtime.h>
#include <math.h>

#define NN 50000
#define KK 16
#define FIN 140
#define HH 8
#define HID 128

// Persistent-grid geometry: 768 blocks * 256 thr, __launch_bounds__(256,3)
// -> VGPR cap 168, 3 blocks/CU on 256 CUs, all blocks co-resident (LDS=0).
#define NBLK 768
#define NWAVES (NBLK * 4)       // 3072 waves
#define NPAIRS 1563             // ceil(3125 16-row tiles / 2)

typedef __attribute__((ext_vector_type(8))) short short8;   // 8 bf16 = 4 VGPRs
typedef __attribute__((ext_vector_type(4))) float f32x4;    // MFMA acc

__device__ inline unsigned short f2bf(float f) {            // RNE fp32->bf16
  unsigned int u = __float_as_uint(f);
  return (unsigned short)((u + 0x7fffu + ((u >> 16) & 1u)) >> 16);
}
__device__ inline float bf2f(unsigned short h) {
  return __uint_as_float(((unsigned int)h) << 16);
}

// ---------------- device-scope grid barrier (monotonic counter) -------------
// All 768 blocks are co-resident by construction. Leader thread releases its
// block's stores (L2 writeback via agent-scope release), arrives, spins with
// acquire loads (L1/L2 invalidate) until all blocks of this phase arrived.
__device__ inline void gbar(unsigned* cnt, unsigned tgt) {
  __syncthreads();                       // drains vmcnt -> block stores in L2
  if (threadIdx.x == 0) {
    __threadfence();                     // agent-scope release fence (wbl2)
    __hip_atomic_fetch_add(cnt, 1u, __ATOMIC_ACQ_REL, __HIP_MEMORY_SCOPE_AGENT);
    long spins = 0;
    for (;;) {
      unsigned v = __hip_atomic_load(cnt, __ATOMIC_ACQUIRE, __HIP_MEMORY_SCOPE_AGENT);
      if (v >= tgt) break;
      if (++spins > (1L << 30)) break;   // safety bailout: never hang the queue
      __builtin_amdgcn_s_sleep(1);
    }
  }
  __syncthreads();                       // block waits on leader's acquire
}

// ---------------- stage bodies (same math as the 6-kernel version) ----------

// Build W^T A-operand fragment tables (hi/lo bf16 split) for pca_w and both Ws.
__device__ inline void prep_work(int gid, const float* __restrict__ pca_w,
                                 const float* __restrict__ Ws,
                                 unsigned short* __restrict__ frags) {
  const float* W; int K; unsigned short *dh, *dl; int tid;
  if (gid < 20480)      { W = pca_w;          K = FIN; dh = frags;                 dl = dh + 20480; tid = gid; }
  else if (gid < 36864) { W = Ws;             K = HID; dh = frags + 40960;         dl = dh + 16384; tid = gid - 20480; }
  else                  { W = Ws + HID * HID; K = HID; dh = frags + 40960 + 32768; dl = dh + 16384; tid = gid - 36864; }
  const int j = tid & 7, L = (tid >> 3) & 63, ct = tid >> 9, t = ct & 7, c = ct >> 3;
  const int k = c * 32 + (L >> 4) * 8 + j;
  const int col = t * 16 + (L & 15);
  const float v = (k < K) ? W[(size_t)k * HID + col] : 0.f;
  const unsigned short h = f2bf(v);
  dh[tid] = h;
  dl[tid] = f2bf(v - bf2f(h));
}

// x = relu(feature @ pca_w + b) -> bf16. TWO 16-node tiles per wave.
__device__ inline void pca_work(int pair, int lane, const float* __restrict__ feat,
                                const unsigned short* __restrict__ wfh,
                                const unsigned short* __restrict__ wfl,
                                const float* __restrict__ b,
                                unsigned short* __restrict__ xbf) {
  const int col = lane & 15, quad = lane >> 4;
  const int tile0 = pair * 2;
  const int tile1 = tile0 + 1;
  const bool has1 = (tile1 < NN / 16);
  const int n0 = tile0 * 16, n1 = tile1 * 16;
  f32x4 acc0[8], acc1[8];
#pragma unroll
  for (int t = 0; t < 8; ++t) {
    acc0[t] = (f32x4){0.f, 0.f, 0.f, 0.f};
    acc1[t] = (f32x4){0.f, 0.f, 0.f, 0.f};
  }
  const float* brow0 = feat + (size_t)(n0 + col) * FIN + quad * 8;
  const float* brow1 = feat + (size_t)((has1 ? n1 : n0) + col) * FIN + quad * 8;
#pragma unroll
  for (int c = 0; c < 5; ++c) {
    float4 a0, a1, c0, c1;
    if (c < 4) {
      a0 = *(const float4*)(brow0 + c * 32);
      a1 = *(const float4*)(brow0 + c * 32 + 4);
      c0 = *(const float4*)(brow1 + c * 32);
      c1 = *(const float4*)(brow1 + c * 32 + 4);
    } else {  // chunk 4: k = 128 + quad*8 + j, valid only k < 140
      a0 = make_float4(0.f, 0.f, 0.f, 0.f); a1 = a0; c0 = a0; c1 = a0;
      if (quad == 0) {
        a0 = *(const float4*)(brow0 + 128); a1 = *(const float4*)(brow0 + 132);
        c0 = *(const float4*)(brow1 + 128); c1 = *(const float4*)(brow1 + 132);
      } else if (quad == 1) {
        a0 = *(const float4*)(brow0 + 128);
        c0 = *(const float4*)(brow1 + 128);
      }
    }
    short8 B0, B1;
    B0[0] = (short)f2bf(a0.x); B0[1] = (short)f2bf(a0.y);
    B0[2] = (short)f2bf(a0.z); B0[3] = (short)f2bf(a0.w);
    B0[4] = (short)f2bf(a1.x); B0[5] = (short)f2bf(a1.y);
    B0[6] = (short)f2bf(a1.z); B0[7] = (short)f2bf(a1.w);
    B1[0] = (short)f2bf(c0.x); B1[1] = (short)f2bf(c0.y);
    B1[2] = (short)f2bf(c0.z); B1[3] = (short)f2bf(c0.w);
    B1[4] = (short)f2bf(c1.x); B1[5] = (short)f2bf(c1.y);
    B1[6] = (short)f2bf(c1.z); B1[7] = (short)f2bf(c1.w);
#pragma unroll
    for (int t = 0; t < 8; ++t) {
      const short8 Ah = *(const short8*)(wfh + ((size_t)(c * 8 + t) * 64 + lane) * 8);
      const short8 Al = *(const short8*)(wfl + ((size_t)(c * 8 + t) * 64 + lane) * 8);
      acc0[t] = __builtin_amdgcn_mfma_f32_16x16x32_bf16(Al, B0, acc0[t], 0, 0, 0);
      acc0[t] = __builtin_amdgcn_mfma_f32_16x16x32_bf16(Ah, B0, acc0[t], 0, 0, 0);
      acc1[t] = __builtin_amdgcn_mfma_f32_16x16x32_bf16(Al, B1, acc1[t], 0, 0, 0);
      acc1[t] = __builtin_amdgcn_mfma_f32_16x16x32_bf16(Ah, B1, acc1[t], 0, 0, 0);
    }
  }
#pragma unroll
  for (int t = 0; t < 8; ++t) {
    const float4 bv = *(const float4*)(b + t * 16 + quad * 4);
    {
      const float v0 = fmaxf(acc0[t][0] + bv.x, 0.f);
      const float v1 = fmaxf(acc0[t][1] + bv.y, 0.f);
      const float v2 = fmaxf(acc0[t][2] + bv.z, 0.f);
      const float v3 = fmaxf(acc0[t][3] + bv.w, 0.f);
      uint2 pk;
      pk.x = (unsigned)f2bf(v0) | ((unsigned)f2bf(v1) << 16);
      pk.y = (unsigned)f2bf(v2) | ((unsigned)f2bf(v3) << 16);
      *(uint2*)&xbf[(size_t)(n0 + col) * HID + t * 16 + quad * 4] = pk;
    }
    if (has1) {
      const float v0 = fmaxf(acc1[t][0] + bv.x, 0.f);
      const float v1 = fmaxf(acc1[t][1] + bv.y, 0.f);
      const float v2 = fmaxf(acc1[t][2] + bv.z, 0.f);
      const float v3 = fmaxf(acc1[t][3] + bv.w, 0.f);
      uint2 pk;
      pk.x = (unsigned)f2bf(v0) | ((unsigned)f2bf(v1) << 16);
      pk.y = (unsigned)f2bf(v2) | ((unsigned)f2bf(v3) << 16);
      *(uint2*)&xbf[(size_t)(n1 + col) * HID + t * 16 + quad * 4] = pk;
    }
  }
}

// h = x@W + b (bf16 store); s_src/s_dst per head. TWO tiles per wave.
__device__ inline void proj_work(int pair, int lane,
                                 const unsigned short* __restrict__ xbf,
                                 const unsigned short* __restrict__ wfh,
                                 const unsigned short* __restrict__ wfl,
                                 const float* __restrict__ b,
                                 const float* __restrict__ asrc,
                                 const float* __restrict__ adst,
                                 unsigned short* __restrict__ hbf,
                                 float* __restrict__ ssrc,
                                 float* __restrict__ sdst) {
  const int col = lane & 15, quad = lane >> 4;
  const int tile0 = pair * 2;
  const int tile1 = tile0 + 1;
  const bool has1 = (tile1 < NN / 16);
  const int n0 = tile0 * 16, n1 = tile1 * 16;
  f32x4 acc0[8], acc1[8];
#pragma unroll
  for (int t = 0; t < 8; ++t) {
    acc0[t] = (f32x4){0.f, 0.f, 0.f, 0.f};
    acc1[t] = (f32x4){0.f, 0.f, 0.f, 0.f};
  }
  const unsigned short* brow0 = xbf + (size_t)(n0 + col) * HID + quad * 8;
  const unsigned short* brow1 = xbf + (size_t)((has1 ? n1 : n0) + col) * HID + quad * 8;
  short8 B0[4], B1[4];
#pragma unroll
  for (int c = 0; c < 4; ++c) {
    B0[c] = *(const short8*)(brow0 + c * 32);
    B1[c] = *(const short8*)(brow1 + c * 32);
  }
#pragma unroll
  for (int c = 0; c < 4; ++c) {
#pragma unroll
    for (int t = 0; t < 8; ++t) {
      const short8 Ah = *(const short8*)(wfh + ((size_t)(c * 8 + t) * 64 + lane) * 8);
      const short8 Al = *(const short8*)(wfl + ((size_t)(c * 8 + t) * 64 + lane) * 8);
      acc0[t] = __builtin_amdgcn_mfma_f32_16x16x32_bf16(Al, B0[c], acc0[t], 0, 0, 0);
      acc0[t] = __builtin_amdgcn_mfma_f32_16x16x32_bf16(Ah, B0[c], acc0[t], 0, 0, 0);
      acc1[t] = __builtin_amdgcn_mfma_f32_16x16x32_bf16(Al, B1[c], acc1[t], 0, 0, 0);
      acc1[t] = __builtin_amdgcn_mfma_f32_16x16x32_bf16(Ah, B1[c], acc1[t], 0, 0, 0);
    }
  }
#pragma unroll
  for (int t = 0; t < 8; ++t) {
    const float4 bv = *(const float4*)(b + t * 16 + quad * 4);
    const float4 av = *(const float4*)(asrc + t * 16 + quad * 4);
    const float4 dv = *(const float4*)(adst + t * 16 + quad * 4);
#pragma unroll
    for (int p = 0; p < 2; ++p) {
      if (p == 1 && !has1) break;
      const f32x4& a = p ? acc1[t] : acc0[t];
      const int nb_ = p ? n1 : n0;
      const float v0 = a[0] + bv.x;
      const float v1 = a[1] + bv.y;
      const float v2 = a[2] + bv.z;
      const float v3 = a[3] + bv.w;
      uint2 pk;
      pk.x = (unsigned)f2bf(v0) | ((unsigned)f2bf(v1) << 16);
      pk.y = (unsigned)f2bf(v2) | ((unsigned)f2bf(v3) << 16);
      *(uint2*)&hbf[(size_t)(nb_ + col) * HID + t * 16 + quad * 4] = pk;
      float ps = v0 * av.x + v1 * av.y + v2 * av.z + v3 * av.w;
      float pd = v0 * dv.x + v1 * dv.y + v2 * dv.z + v3 * dv.w;
      ps += __shfl_xor(ps, 16); ps += __shfl_xor(ps, 32);
      pd += __shfl_xor(pd, 16); pd += __shfl_xor(pd, 32);
      if (quad == 0) ssrc[(size_t)(nb_ + col) * HH + t] = ps;
      if (quad == 1) sdst[(size_t)(nb_ + col) * HH + t] = pd;
    }
  }
}

// attn body: one wave handles a PAIR of nodes per iteration (2-node ILP).
template <bool LAST>
__device__ inline void attn_body(
    const int* __restrict__ nb, const unsigned int* __restrict__ hbf,
    const float* __restrict__ ssrc, const float* __restrict__ sdst,
    void* __restrict__ xout, int lane, int wid, int nwaves) {
  for (int base = wid * 2; base < NN; base += nwaves * 2) {
    const int nA = base, nB = base + 1;
    int nbv = 0;
    if (lane < KK) nbv = nb[(size_t)nA * KK + lane];
    else if (lane < 2 * KK) nbv = nb[(size_t)nB * KK + (lane - KK)];
    unsigned int uA[KK], uB[KK];
#pragma unroll
    for (int k = 0; k < KK; ++k) {
      const int rA = __shfl(nbv, k);
      uA[k] = hbf[(size_t)rA * (HID / 2) + lane];
    }
#pragma unroll
    for (int k = 0; k < KK; ++k) {
      const int rB = __shfl(nbv, KK + k);
      uB[k] = hbf[(size_t)rB * (HID / 2) + lane];
    }
    const int h = lane & 7, k0 = lane >> 3;
    const int rA0 = __shfl(nbv, k0), rA1 = __shfl(nbv, k0 + 8);
    const int rB0 = __shfl(nbv, KK + k0), rB1 = __shfl(nbv, KK + k0 + 8);
    const float ssA = ssrc[(size_t)nA * HH + h];
    const float ssB = ssrc[(size_t)nB * HH + h];
    float eA0 = ssA + sdst[(size_t)rA0 * HH + h];
    float eA1 = ssA + sdst[(size_t)rA1 * HH + h];
    float eB0 = ssB + sdst[(size_t)rB0 * HH + h];
    float eB1 = ssB + sdst[(size_t)rB1 * HH + h];
    eA0 = eA0 > 0.f ? eA0 : 0.2f * eA0;
    eA1 = eA1 > 0.f ? eA1 : 0.2f * eA1;
    eB0 = eB0 > 0.f ? eB0 : 0.2f * eB0;
    eB1 = eB1 > 0.f ? eB1 : 0.2f * eB1;
    float mA = fmaxf(eA0, eA1), mB = fmaxf(eB0, eB1);
    mA = fmaxf(mA, __shfl_xor(mA, 8));  mB = fmaxf(mB, __shfl_xor(mB, 8));
    mA = fmaxf(mA, __shfl_xor(mA, 16)); mB = fmaxf(mB, __shfl_xor(mB, 16));
    mA = fmaxf(mA, __shfl_xor(mA, 32)); mB = fmaxf(mB, __shfl_xor(mB, 32));
    float pA0 = __expf(eA0 - mA), pA1 = __expf(eA1 - mA);
    float pB0 = __expf(eB0 - mB), pB1 = __expf(eB1 - mB);
    float sA = pA0 + pA1, sB = pB0 + pB1;
    sA += __shfl_xor(sA, 8);  sB += __shfl_xor(sB, 8);
    sA += __shfl_xor(sA, 16); sB += __shfl_xor(sB, 16);
    sA += __shfl_xor(sA, 32); sB += __shfl_xor(sB, 32);
    const float invA = 1.f / sA, invB = 1.f / sB;
    pA0 *= invA; pA1 *= invA; pB0 *= invB; pB1 *= invB;
    const int head = lane >> 3;
    float aA0 = 0.f, aA1 = 0.f, aB0 = 0.f, aB1 = 0.f;
#pragma unroll
    for (int k = 0; k < KK; ++k) {
      const float selA = (k < 8) ? pA0 : pA1;
      const float selB = (k < 8) ? pB0 : pB1;
      const float wA = __shfl(selA, ((k & 7) << 3) + head);
      const float wB = __shfl(selB, ((k & 7) << 3) + head);
      aA0 = fmaf(wA, __uint_as_float(uA[k] << 16), aA0);
      aA1 = fmaf(wA, __uint_as_float(uA[k] & 0xffff0000u), aA1);
      aB0 = fmaf(wB, __uint_as_float(uB[k] << 16), aB0);
      aB1 = fmaf(wB, __uint_as_float(uB[k] & 0xffff0000u), aB1);
    }
    const float oA0 = aA0 > 0.f ? aA0 : __expf(aA0) - 1.f;
    const float oA1 = aA1 > 0.f ? aA1 : __expf(aA1) - 1.f;
    const float oB0 = aB0 > 0.f ? aB0 : __expf(aB0) - 1.f;
    const float oB1 = aB1 > 0.f ? aB1 : __expf(aB1) - 1.f;
    if (LAST) {
      *(float2*)((float*)xout + (size_t)nA * HID + 2 * lane) = make_float2(oA0, oA1);
      *(float2*)((float*)xout + (size_t)nB * HID + 2 * lane) = make_float2(oB0, oB1);
    } else {
      ((unsigned int*)xout)[(size_t)nA * (HID / 2) + lane] =
          (unsigned)f2bf(oA0) | ((unsigned)f2bf(oA1) << 16);
      ((unsigned int*)xout)[(size_t)nB * (HID / 2) + lane] =
          (unsigned)f2bf(oB0) | ((unsigned)f2bf(oB1) << 16);
    }
  }
}

// ---------------- single persistent fused kernel ----------------------------
__global__ __launch_bounds__(256, 3) void fused_gat(
    const float* __restrict__ feat, const int* __restrict__ nb,
    const float* __restrict__ pca_w, const float* __restrict__ pca_b,
    const float* __restrict__ Ws, const float* __restrict__ bs,
    const float* __restrict__ a_src, const float* __restrict__ a_dst,
    float* __restrict__ out, unsigned short* __restrict__ xbf,
    unsigned short* __restrict__ hbf, float* __restrict__ ssrc,
    float* __restrict__ sdst, unsigned short* __restrict__ frags,
    unsigned* __restrict__ barcnt) {
  const int tid = threadIdx.x;
  const int lane = tid & 63;
  const int wid = ((int)blockIdx.x << 2) + (tid >> 6);
  const int gid = (int)blockIdx.x * 256 + tid;

  // stage 0: weight fragment prep (53248 work items)
  if (gid < 53248) prep_work(gid, pca_w, Ws, frags);
  gbar(barcnt, NBLK * 1);

  // stage 1: x0 = relu(feature @ pca_w + b)
  if (wid < NPAIRS) pca_work(wid, lane, feat, frags, frags + 20480, pca_b, xbf);
  gbar(barcnt, NBLK * 2);

  // stage 2: layer-0 projection
  if (wid < NPAIRS)
    proj_work(wid, lane, xbf, frags + 40960, frags + 40960 + 16384,
              bs, a_src, a_dst, hbf, ssrc, sdst);
  gbar(barcnt, NBLK * 3);

  // stage 3: layer-0 attention -> xbf (bf16)
  attn_body<false>(nb, (const unsigned int*)hbf, ssrc, sdst, (void*)xbf,
                   lane, wid, NWAVES);
  gbar(barcnt, NBLK * 4);

  // stage 4: layer-1 projection
  if (wid < NPAIRS)
    proj_work(wid, lane, xbf, frags + 40960 + 32768, frags + 40960 + 32768 + 16384,
              bs + HID, a_src + HID, a_dst + HID, hbf, ssrc, sdst);
  gbar(barcnt, NBLK * 5);

  // stage 5: layer-1 attention -> out (f32)
  attn_body<true>(nb, (const unsigned int*)hbf, ssrc, sdst, (void*)out,
                  lane, wid, NWAVES);
}

extern "C" void kernel_launch(void* const* d_in, const int* in_sizes, int n_in,
                              void* d_out, int out_size, void* d_ws, size_t ws_size,
                              hipStream_t stream) {
  const float* feature = (const float*)d_in[0];
  const int*   nb      = (const int*)d_in[1];
  const float* pca_w   = (const float*)d_in[2];
  const float* pca_b   = (const float*)d_in[3];
  const float* Ws      = (const float*)d_in[4];
  const float* bs      = (const float*)d_in[5];
  const float* a_src   = (const float*)d_in[6];
  const float* a_dst   = (const float*)d_in[7];
  float* out = (float*)d_out;

  unsigned short* xbf = (unsigned short*)d_ws;                 // [N,128] bf16
  unsigned short* hbf = xbf + (size_t)NN * HID;                // [N,128] bf16
  float* ssrc = (float*)(hbf + (size_t)NN * HID);              // [N,8]
  float* sdst = ssrc + (size_t)NN * HH;                        // [N,8]
  unsigned short* frags = (unsigned short*)(sdst + (size_t)NN * HH); // 106496 shorts
  // barrier counter: 256B-aligned, right after frags
  size_t bar_off = ((size_t)((char*)(frags + 106496) - (char*)d_ws) + 255) & ~(size_t)255;
  unsigned* barcnt = (unsigned*)((char*)d_ws + bar_off);

  hipMemsetAsync(barcnt, 0, 256, stream);   // capturable memset node
  fused_gat<<<NBLK, 256, 0, stream>>>(feature, nb, pca_w, pca_b, Ws, bs,
                                      a_src, a_dst, out, xbf, hbf, ssrc, sdst,
                                      frags, barcnt);
}

// Round 2
// 653.211 us; speedup vs baseline: 1.6053x; 1.6053x over previous
//
#include <hip/hip_runtime.h>
#include <math.h>

#define NN 50000
#define KK 16
#define FIN 140
#define HH 8
#define HID 128

// Persistent-grid geometry: 1024 blocks * 256 thr, __launch_bounds__(256,4)
// -> VGPR cap 128, 4 blocks/CU on 256 CUs, all blocks co-resident (LDS=0).
#define NBLK 1024
#define NWAVES (NBLK * 4)       // 4096 waves
#define NPAIRS 1563             // ceil(3125 16-row tiles / 2)

typedef __attribute__((ext_vector_type(8))) short short8;   // 8 bf16 = 4 VGPRs
typedef __attribute__((ext_vector_type(4))) float f32x4;    // MFMA acc

__device__ inline unsigned short f2bf(float f) {            // RNE fp32->bf16
  unsigned int u = __float_as_uint(f);
  return (unsigned short)((u + 0x7fffu + ((u >> 16) & 1u)) >> 16);
}
__device__ inline float bf2f(unsigned short h) {
  return __uint_as_float(((unsigned int)h) << 16);
}

// ---------------- device-scope grid barrier (monotonic counter) -------------
// R1 lesson: polling with ACQUIRE at agent scope emits buffer_inv per poll ->
// continuous L1/L2 invalidation storm (FETCH_SIZE 247 MB, 5x slowdown).
// Fix: RELEASE on arrival (one wbL2), RELAXED polling (cache-bypassing load,
// NO invalidates), then exactly ONE __threadfence() invalidate after the
// count trips. 4 barriers * 1024 blocks = 4096 invalidates total.
__device__ inline void gbar(unsigned* cnt, unsigned tgt) {
  __syncthreads();                       // drains vmcnt -> block stores in L2
  if (threadIdx.x == 0) {
    __hip_atomic_fetch_add(cnt, 1u, __ATOMIC_RELEASE, __HIP_MEMORY_SCOPE_AGENT);
    long spins = 0;
    for (;;) {
      unsigned v = __hip_atomic_load(cnt, __ATOMIC_RELAXED, __HIP_MEMORY_SCOPE_AGENT);
      if (v >= tgt) break;
      if (++spins > (1L << 26)) break;   // safety bailout: never hang the queue
      __builtin_amdgcn_s_sleep(2);
    }
    __threadfence();                     // single acquire-side inv (L1+L2)
  }
  __syncthreads();                       // block waits on leader
}

// ---------------- stage bodies (same math as the 6-kernel version) ----------

// Build W^T A-operand fragment tables (hi/lo bf16 split) for pca_w and both Ws.
__device__ inline void prep_work(int gid, const float* __restrict__ pca_w,
                                 const float* __restrict__ Ws,
                                 unsigned short* __restrict__ frags) {
  const float* W; int K; unsigned short *dh, *dl; int tid;
  if (gid < 20480)      { W = pca_w;          K = FIN; dh = frags;                 dl = dh + 20480; tid = gid; }
  else if (gid < 36864) { W = Ws;             K = HID; dh = frags + 40960;         dl = dh + 16384; tid = gid - 20480; }
  else                  { W = Ws + HID * HID; K = HID; dh = frags + 40960 + 32768; dl = dh + 16384; tid = gid - 36864; }
  const int j = tid & 7, L = (tid >> 3) & 63, ct = tid >> 9, t = ct & 7, c = ct >> 3;
  const int k = c * 32 + (L >> 4) * 8 + j;
  const int col = t * 16 + (L & 15);
  const float v = (k < K) ? W[(size_t)k * HID + col] : 0.f;
  const unsigned short h = f2bf(v);
  dh[tid] = h;
  dl[tid] = f2bf(v - bf2f(h));
}

// x = relu(feature @ pca_w + b) -> bf16. TWO 16-node tiles per wave.
__device__ inline void pca_work(int pair, int lane, const float* __restrict__ feat,
                                const unsigned short* __restrict__ wfh,
                                const unsigned short* __restrict__ wfl,
                                const float* __restrict__ b,
                                unsigned short* __restrict__ xbf) {
  const int col = lane & 15, quad = lane >> 4;
  const int tile0 = pair * 2;
  const int tile1 = tile0 + 1;
  const bool has1 = (tile1 < NN / 16);
  const int n0 = tile0 * 16, n1 = tile1 * 16;
  f32x4 acc0[8], acc1[8];
#pragma unroll
  for (int t = 0; t < 8; ++t) {
    acc0[t] = (f32x4){0.f, 0.f, 0.f, 0.f};
    acc1[t] = (f32x4){0.f, 0.f, 0.f, 0.f};
  }
  const float* brow0 = feat + (size_t)(n0 + col) * FIN + quad * 8;
  const float* brow1 = feat + (size_t)((has1 ? n1 : n0) + col) * FIN + quad * 8;
#pragma unroll
  for (int c = 0; c < 5; ++c) {
    float4 a0, a1, c0, c1;
    if (c < 4) {
      a0 = *(const float4*)(brow0 + c * 32);
      a1 = *(const float4*)(brow0 + c * 32 + 4);
      c0 = *(const float4*)(brow1 + c * 32);
      c1 = *(const float4*)(brow1 + c * 32 + 4);
    } else {  // chunk 4: k = 128 + quad*8 + j, valid only k < 140
      a0 = make_float4(0.f, 0.f, 0.f, 0.f); a1 = a0; c0 = a0; c1 = a0;
      if (quad == 0) {
        a0 = *(const float4*)(brow0 + 128); a1 = *(const float4*)(brow0 + 132);
        c0 = *(const float4*)(brow1 + 128); c1 = *(const float4*)(brow1 + 132);
      } else if (quad == 1) {
        a0 = *(const float4*)(brow0 + 128);
        c0 = *(const float4*)(brow1 + 128);
      }
    }
    short8 B0, B1;
    B0[0] = (short)f2bf(a0.x); B0[1] = (short)f2bf(a0.y);
    B0[2] = (short)f2bf(a0.z); B0[3] = (short)f2bf(a0.w);
    B0[4] = (short)f2bf(a1.x); B0[5] = (short)f2bf(a1.y);
    B0[6] = (short)f2bf(a1.z); B0[7] = (short)f2bf(a1.w);
    B1[0] = (short)f2bf(c0.x); B1[1] = (short)f2bf(c0.y);
    B1[2] = (short)f2bf(c0.z); B1[3] = (short)f2bf(c0.w);
    B1[4] = (short)f2bf(c1.x); B1[5] = (short)f2bf(c1.y);
    B1[6] = (short)f2bf(c1.z); B1[7] = (short)f2bf(c1.w);
#pragma unroll
    for (int t = 0; t < 8; ++t) {
      const short8 Ah = *(const short8*)(wfh + ((size_t)(c * 8 + t) * 64 + lane) * 8);
      const short8 Al = *(const short8*)(wfl + ((size_t)(c * 8 + t) * 64 + lane) * 8);
      acc0[t] = __builtin_amdgcn_mfma_f32_16x16x32_bf16(Al, B0, acc0[t], 0, 0, 0);
      acc0[t] = __builtin_amdgcn_mfma_f32_16x16x32_bf16(Ah, B0, acc0[t], 0, 0, 0);
      acc1[t] = __builtin_amdgcn_mfma_f32_16x16x32_bf16(Al, B1, acc1[t], 0, 0, 0);
      acc1[t] = __builtin_amdgcn_mfma_f32_16x16x32_bf16(Ah, B1, acc1[t], 0, 0, 0);
    }
  }
#pragma unroll
  for (int t = 0; t < 8; ++t) {
    const float4 bv = *(const float4*)(b + t * 16 + quad * 4);
    {
      const float v0 = fmaxf(acc0[t][0] + bv.x, 0.f);
      const float v1 = fmaxf(acc0[t][1] + bv.y, 0.f);
      const float v2 = fmaxf(acc0[t][2] + bv.z, 0.f);
      const float v3 = fmaxf(acc0[t][3] + bv.w, 0.f);
      uint2 pk;
      pk.x = (unsigned)f2bf(v0) | ((unsigned)f2bf(v1) << 16);
      pk.y = (unsigned)f2bf(v2) | ((unsigned)f2bf(v3) << 16);
      *(uint2*)&xbf[(size_t)(n0 + col) * HID + t * 16 + quad * 4] = pk;
    }
    if (has1) {
      const float v0 = fmaxf(acc1[t][0] + bv.x, 0.f);
      const float v1 = fmaxf(acc1[t][1] + bv.y, 0.f);
      const float v2 = fmaxf(acc1[t][2] + bv.z, 0.f);
      const float v3 = fmaxf(acc1[t][3] + bv.w, 0.f);
      uint2 pk;
      pk.x = (unsigned)f2bf(v0) | ((unsigned)f2bf(v1) << 16);
      pk.y = (unsigned)f2bf(v2) | ((unsigned)f2bf(v3) << 16);
      *(uint2*)&xbf[(size_t)(n1 + col) * HID + t * 16 + quad * 4] = pk;
    }
  }
}

// h = x@W + b (bf16 store); s_src/s_dst per head. TWO tiles per wave.
__device__ inline void proj_work(int pair, int lane,
                                 const unsigned short* __restrict__ xbf,
                                 const unsigned short* __restrict__ wfh,
                                 const unsigned short* __restrict__ wfl,
                                 const float* __restrict__ b,
                                 const float* __restrict__ asrc,
                                 const float* __restrict__ adst,
                                 unsigned short* __restrict__ hbf,
                                 float* __restrict__ ssrc,
                                 float* __restrict__ sdst) {
  const int col = lane & 15, quad = lane >> 4;
  const int tile0 = pair * 2;
  const int tile1 = tile0 + 1;
  const bool has1 = (tile1 < NN / 16);
  const int n0 = tile0 * 16, n1 = tile1 * 16;
  f32x4 acc0[8], acc1[8];
#pragma unroll
  for (int t = 0; t < 8; ++t) {
    acc0[t] = (f32x4){0.f, 0.f, 0.f, 0.f};
    acc1[t] = (f32x4){0.f, 0.f, 0.f, 0.f};
  }
  const unsigned short* brow0 = xbf + (size_t)(n0 + col) * HID + quad * 8;
  const unsigned short* brow1 = xbf + (size_t)((has1 ? n1 : n0) + col) * HID + quad * 8;
  short8 B0[4], B1[4];
#pragma unroll
  for (int c = 0; c < 4; ++c) {
    B0[c] = *(const short8*)(brow0 + c * 32);
    B1[c] = *(const short8*)(brow1 + c * 32);
  }
#pragma unroll
  for (int c = 0; c < 4; ++c) {
#pragma unroll
    for (int t = 0; t < 8; ++t) {
      const short8 Ah = *(const short8*)(wfh + ((size_t)(c * 8 + t) * 64 + lane) * 8);
      const short8 Al = *(const short8*)(wfl + ((size_t)(c * 8 + t) * 64 + lane) * 8);
      acc0[t] = __builtin_amdgcn_mfma_f32_16x16x32_bf16(Al, B0[c], acc0[t], 0, 0, 0);
      acc0[t] = __builtin_amdgcn_mfma_f32_16x16x32_bf16(Ah, B0[c], acc0[t], 0, 0, 0);
      acc1[t] = __builtin_amdgcn_mfma_f32_16x16x32_bf16(Al, B1[c], acc1[t], 0, 0, 0);
      acc1[t] = __builtin_amdgcn_mfma_f32_16x16x32_bf16(Ah, B1[c], acc1[t], 0, 0, 0);
    }
  }
#pragma unroll
  for (int t = 0; t < 8; ++t) {
    const float4 bv = *(const float4*)(b + t * 16 + quad * 4);
    const float4 av = *(const float4*)(asrc + t * 16 + quad * 4);
    const float4 dv = *(const float4*)(adst + t * 16 + quad * 4);
#pragma unroll
    for (int p = 0; p < 2; ++p) {
      if (p == 1 && !has1) break;
      const f32x4& a = p ? acc1[t] : acc0[t];
      const int nb_ = p ? n1 : n0;
      const float v0 = a[0] + bv.x;
      const float v1 = a[1] + bv.y;
      const float v2 = a[2] + bv.z;
      const float v3 = a[3] + bv.w;
      uint2 pk;
      pk.x = (unsigned)f2bf(v0) | ((unsigned)f2bf(v1) << 16);
      pk.y = (unsigned)f2bf(v2) | ((unsigned)f2bf(v3) << 16);
      *(uint2*)&hbf[(size_t)(nb_ + col) * HID + t * 16 + quad * 4] = pk;
      float ps = v0 * av.x + v1 * av.y + v2 * av.z + v3 * av.w;
      float pd = v0 * dv.x + v1 * dv.y + v2 * dv.z + v3 * dv.w;
      ps += __shfl_xor(ps, 16); ps += __shfl_xor(ps, 32);
      pd += __shfl_xor(pd, 16); pd += __shfl_xor(pd, 32);
      if (quad == 0) ssrc[(size_t)(nb_ + col) * HH + t] = ps;
      if (quad == 1) sdst[(size_t)(nb_ + col) * HH + t] = pd;
    }
  }
}

// attn body: one wave handles a PAIR of nodes per iteration (2-node ILP).
template <bool LAST>
__device__ inline void attn_body(
    const int* __restrict__ nb, const unsigned int* __restrict__ hbf,
    const float* __restrict__ ssrc, const float* __restrict__ sdst,
    void* __restrict__ xout, int lane, int wid, int nwaves) {
  for (int base = wid * 2; base < NN; base += nwaves * 2) {
    const int nA = base, nB = base + 1;
    int nbv = 0;
    if (lane < KK) nbv = nb[(size_t)nA * KK + lane];
    else if (lane < 2 * KK) nbv = nb[(size_t)nB * KK + (lane - KK)];
    unsigned int uA[KK], uB[KK];
#pragma unroll
    for (int k = 0; k < KK; ++k) {
      const int rA = __shfl(nbv, k);
      uA[k] = hbf[(size_t)rA * (HID / 2) + lane];
    }
#pragma unroll
    for (int k = 0; k < KK; ++k) {
      const int rB = __shfl(nbv, KK + k);
      uB[k] = hbf[(size_t)rB * (HID / 2) + lane];
    }
    const int h = lane & 7, k0 = lane >> 3;
    const int rA0 = __shfl(nbv, k0), rA1 = __shfl(nbv, k0 + 8);
    const int rB0 = __shfl(nbv, KK + k0), rB1 = __shfl(nbv, KK + k0 + 8);
    const float ssA = ssrc[(size_t)nA * HH + h];
    const float ssB = ssrc[(size_t)nB * HH + h];
    float eA0 = ssA + sdst[(size_t)rA0 * HH + h];
    float eA1 = ssA + sdst[(size_t)rA1 * HH + h];
    float eB0 = ssB + sdst[(size_t)rB0 * HH + h];
    float eB1 = ssB + sdst[(size_t)rB1 * HH + h];
    eA0 = eA0 > 0.f ? eA0 : 0.2f * eA0;
    eA1 = eA1 > 0.f ? eA1 : 0.2f * eA1;
    eB0 = eB0 > 0.f ? eB0 : 0.2f * eB0;
    eB1 = eB1 > 0.f ? eB1 : 0.2f * eB1;
    float mA = fmaxf(eA0, eA1), mB = fmaxf(eB0, eB1);
    mA = fmaxf(mA, __shfl_xor(mA, 8));  mB = fmaxf(mB, __shfl_xor(mB, 8));
    mA = fmaxf(mA, __shfl_xor(mA, 16)); mB = fmaxf(mB, __shfl_xor(mB, 16));
    mA = fmaxf(mA, __shfl_xor(mA, 32)); mB = fmaxf(mB, __shfl_xor(mB, 32));
    float pA0 = __expf(eA0 - mA), pA1 = __expf(eA1 - mA);
    float pB0 = __expf(eB0 - mB), pB1 = __expf(eB1 - mB);
    float sA = pA0 + pA1, sB = pB0 + pB1;
    sA += __shfl_xor(sA, 8);  sB += __shfl_xor(sB, 8);
    sA += __shfl_xor(sA, 16); sB += __shfl_xor(sB, 16);
    sA += __shfl_xor(sA, 32); sB += __shfl_xor(sB, 32);
    const float invA = 1.f / sA, invB = 1.f / sB;
    pA0 *= invA; pA1 *= invA; pB0 *= invB; pB1 *= invB;
    const int head = lane >> 3;
    float aA0 = 0.f, aA1 = 0.f, aB0 = 0.f, aB1 = 0.f;
#pragma unroll
    for (int k = 0; k < KK; ++k) {
      const float selA = (k < 8) ? pA0 : pA1;
      const float selB = (k < 8) ? pB0 : pB1;
      const float wA = __shfl(selA, ((k & 7) << 3) + head);
      const float wB = __shfl(selB, ((k & 7) << 3) + head);
      aA0 = fmaf(wA, __uint_as_float(uA[k] << 16), aA0);
      aA1 = fmaf(wA, __uint_as_float(uA[k] & 0xffff0000u), aA1);
      aB0 = fmaf(wB, __uint_as_float(uB[k] << 16), aB0);
      aB1 = fmaf(wB, __uint_as_float(uB[k] & 0xffff0000u), aB1);
    }
    const float oA0 = aA0 > 0.f ? aA0 : __expf(aA0) - 1.f;
    const float oA1 = aA1 > 0.f ? aA1 : __expf(aA1) - 1.f;
    const float oB0 = aB0 > 0.f ? aB0 : __expf(aB0) - 1.f;
    const float oB1 = aB1 > 0.f ? aB1 : __expf(aB1) - 1.f;
    if (LAST) {
      *(float2*)((float*)xout + (size_t)nA * HID + 2 * lane) = make_float2(oA0, oA1);
      *(float2*)((float*)xout + (size_t)nB * HID + 2 * lane) = make_float2(oB0, oB1);
    } else {
      ((unsigned int*)xout)[(size_t)nA * (HID / 2) + lane] =
          (unsigned)f2bf(oA0) | ((unsigned)f2bf(oA1) << 16);
      ((unsigned int*)xout)[(size_t)nB * (HID / 2) + lane] =
          (unsigned)f2bf(oB0) | ((unsigned)f2bf(oB1) << 16);
    }
  }
}

// ---------------- single persistent fused kernel ----------------------------
__global__ __launch_bounds__(256, 4) void fused_gat(
    const float* __restrict__ feat, const int* __restrict__ nb,
    const float* __restrict__ pca_w, const float* __restrict__ pca_b,
    const float* __restrict__ Ws, const float* __restrict__ bs,
    const float* __restrict__ a_src, const float* __restrict__ a_dst,
    float* __restrict__ out, unsigned short* __restrict__ xbf,
    unsigned short* __restrict__ hbf, float* __restrict__ ssrc,
    float* __restrict__ sdst, unsigned short* __restrict__ frags,
    unsigned* __restrict__ barcnt) {
  const int tid = threadIdx.x;
  const int lane = tid & 63;
  const int wid = ((int)blockIdx.x << 2) + (tid >> 6);
  const int gid = (int)blockIdx.x * 256 + tid;

  // stage 0: weight fragment prep (53248 work items)
  if (gid < 53248) prep_work(gid, pca_w, Ws, frags);
  gbar(barcnt, NBLK * 1);

  // stage 1: x0 = relu(feature @ pca_w + b), then layer-0 projection FUSED.
  // proj0 reads only the 32 xbf rows this same wave just wrote -> no grid
  // barrier needed, just drain this wave's own stores (vmcnt 0); rows are
  // L1/L2-hot on reload.
  if (wid < NPAIRS) {
    pca_work(wid, lane, feat, frags, frags + 20480, pca_b, xbf);
    asm volatile("s_waitcnt vmcnt(0)" ::: "memory");
    proj_work(wid, lane, xbf, frags + 40960, frags + 40960 + 16384,
              bs, a_src, a_dst, hbf, ssrc, sdst);
  }
  gbar(barcnt, NBLK * 2);

  // stage 2: layer-0 attention -> xbf (bf16)
  attn_body<false>(nb, (const unsigned int*)hbf, ssrc, sdst, (void*)xbf,
                   lane, wid, NWAVES);
  gbar(barcnt, NBLK * 3);

  // stage 3: layer-1 projection
  if (wid < NPAIRS)
    proj_work(wid, lane, xbf, frags + 40960 + 32768, frags + 40960 + 32768 + 16384,
              bs + HID, a_src + HID, a_dst + HID, hbf, ssrc, sdst);
  gbar(barcnt, NBLK * 4);

  // stage 4: layer-1 attention -> out (f32)
  attn_body<true>(nb, (const unsigned int*)hbf, ssrc, sdst, (void*)out,
                  lane, wid, NWAVES);
}

extern "C" void kernel_launch(void* const* d_in, const int* in_sizes, int n_in,
                              void* d_out, int out_size, void* d_ws, size_t ws_size,
                              hipStream_t stream) {
  const float* feature = (const float*)d_in[0];
  const int*   nb      = (const int*)d_in[1];
  const float* pca_w   = (const float*)d_in[2];
  const float* pca_b   = (const float*)d_in[3];
  const float* Ws      = (const float*)d_in[4];
  const float* bs      = (const float*)d_in[5];
  const float* a_src   = (const float*)d_in[6];
  const float* a_dst   = (const float*)d_in[7];
  float* out = (float*)d_out;

  unsigned short* xbf = (unsigned short*)d_ws;                 // [N,128] bf16
  unsigned short* hbf = xbf + (size_t)NN * HID;                // [N,128] bf16
  float* ssrc = (float*)(hbf + (size_t)NN * HID);              // [N,8]
  float* sdst = ssrc + (size_t)NN * HH;                        // [N,8]
  unsigned short* frags = (unsigned short*)(sdst + (size_t)NN * HH); // 106496 shorts
  // barrier counter: 256B-aligned, right after frags
  size_t bar_off = ((size_t)((char*)(frags + 106496) - (char*)d_ws) + 255) & ~(size_t)255;
  unsigned* barcnt = (unsigned*)((char*)d_ws + bar_off);

  hipMemsetAsync(barcnt, 0, 256, stream);   // capturable memset node
  fused_gat<<<NBLK, 256, 0, stream>>>(feature, nb, pca_w, pca_b, Ws, bs,
                                      a_src, a_dst, out, xbf, hbf, ssrc, sdst,
                                      frags, barcnt);
}

// Round 3
// 225.405 us; speedup vs baseline: 4.6520x; 2.8979x over previous
//
#include <hip/hip_runtime.h>
#include <math.h>

#define NN 50000
#define KK 16
#define FIN 140
#define HH 8
#define HID 128

typedef __attribute__((ext_vector_type(8))) short short8;   // 8 bf16 = 4 VGPRs
typedef __attribute__((ext_vector_type(4))) float f32x4;    // MFMA acc

__device__ inline unsigned short f2bf(float f) {            // RNE fp32->bf16
  unsigned int u = __float_as_uint(f);
  return (unsigned short)((u + 0x7fffu + ((u >> 16) & 1u)) >> 16);
}
__device__ inline float bf2f(unsigned short h) {
  return __uint_as_float(((unsigned int)h) << 16);
}

// Build W^T A-operand fragment tables (hi/lo bf16 split) for pca_w and both Ws.
__global__ __launch_bounds__(256) void prep_kernel(
    const float* __restrict__ pca_w, const float* __restrict__ Ws,
    unsigned short* __restrict__ frags) {
  const int gid = blockIdx.x * 256 + threadIdx.x;   // 208*256 = 53248 exact
  const float* W; int K; unsigned short *dh, *dl; int tid;
  if (gid < 20480)      { W = pca_w;          K = FIN; dh = frags;                 dl = dh + 20480; tid = gid; }
  else if (gid < 36864) { W = Ws;             K = HID; dh = frags + 40960;         dl = dh + 16384; tid = gid - 20480; }
  else                  { W = Ws + HID * HID; K = HID; dh = frags + 40960 + 32768; dl = dh + 16384; tid = gid - 36864; }
  const int j = tid & 7, L = (tid >> 3) & 63, ct = tid >> 9, t = ct & 7, c = ct >> 3;
  const int k = c * 32 + (L >> 4) * 8 + j;
  const int col = t * 16 + (L & 15);
  const float v = (k < K) ? W[(size_t)k * HID + col] : 0.f;
  const unsigned short h = f2bf(v);
  dh[tid] = h;
  dl[tid] = f2bf(v - bf2f(h));
}

// x = relu(feature @ pca_w + b) -> bf16. TWO 16-node tiles per wave.
__device__ inline void pca_work(int pair, int lane, const float* __restrict__ feat,
                                const unsigned short* __restrict__ wfh,
                                const unsigned short* __restrict__ wfl,
                                const float* __restrict__ b,
                                unsigned short* __restrict__ xbf) {
  const int col = lane & 15, quad = lane >> 4;
  const int tile0 = pair * 2;
  const int tile1 = tile0 + 1;
  const bool has1 = (tile1 < NN / 16);
  const int n0 = tile0 * 16, n1 = tile1 * 16;
  f32x4 acc0[8], acc1[8];
#pragma unroll
  for (int t = 0; t < 8; ++t) {
    acc0[t] = (f32x4){0.f, 0.f, 0.f, 0.f};
    acc1[t] = (f32x4){0.f, 0.f, 0.f, 0.f};
  }
  const float* brow0 = feat + (size_t)(n0 + col) * FIN + quad * 8;
  const float* brow1 = feat + (size_t)((has1 ? n1 : n0) + col) * FIN + quad * 8;
#pragma unroll
  for (int c = 0; c < 5; ++c) {
    float4 a0, a1, c0, c1;
    if (c < 4) {
      a0 = *(const float4*)(brow0 + c * 32);
      a1 = *(const float4*)(brow0 + c * 32 + 4);
      c0 = *(const float4*)(brow1 + c * 32);
      c1 = *(const float4*)(brow1 + c * 32 + 4);
    } else {  // chunk 4: k = 128 + quad*8 + j, valid only k < 140
      a0 = make_float4(0.f, 0.f, 0.f, 0.f); a1 = a0; c0 = a0; c1 = a0;
      if (quad == 0) {
        a0 = *(const float4*)(brow0 + 128); a1 = *(const float4*)(brow0 + 132);
        c0 = *(const float4*)(brow1 + 128); c1 = *(const float4*)(brow1 + 132);
      } else if (quad == 1) {
        a0 = *(const float4*)(brow0 + 128);
        c0 = *(const float4*)(brow1 + 128);
      }
    }
    short8 B0, B1;
    B0[0] = (short)f2bf(a0.x); B0[1] = (short)f2bf(a0.y);
    B0[2] = (short)f2bf(a0.z); B0[3] = (short)f2bf(a0.w);
    B0[4] = (short)f2bf(a1.x); B0[5] = (short)f2bf(a1.y);
    B0[6] = (short)f2bf(a1.z); B0[7] = (short)f2bf(a1.w);
    B1[0] = (short)f2bf(c0.x); B1[1] = (short)f2bf(c0.y);
    B1[2] = (short)f2bf(c0.z); B1[3] = (short)f2bf(c0.w);
    B1[4] = (short)f2bf(c1.x); B1[5] = (short)f2bf(c1.y);
    B1[6] = (short)f2bf(c1.z); B1[7] = (short)f2bf(c1.w);
#pragma unroll
    for (int t = 0; t < 8; ++t) {
      const short8 Ah = *(const short8*)(wfh + ((size_t)(c * 8 + t) * 64 + lane) * 8);
      const short8 Al = *(const short8*)(wfl + ((size_t)(c * 8 + t) * 64 + lane) * 8);
      acc0[t] = __builtin_amdgcn_mfma_f32_16x16x32_bf16(Al, B0, acc0[t], 0, 0, 0);
      acc0[t] = __builtin_amdgcn_mfma_f32_16x16x32_bf16(Ah, B0, acc0[t], 0, 0, 0);
      acc1[t] = __builtin_amdgcn_mfma_f32_16x16x32_bf16(Al, B1, acc1[t], 0, 0, 0);
      acc1[t] = __builtin_amdgcn_mfma_f32_16x16x32_bf16(Ah, B1, acc1[t], 0, 0, 0);
    }
  }
#pragma unroll
  for (int t = 0; t < 8; ++t) {
    const float4 bv = *(const float4*)(b + t * 16 + quad * 4);
    {
      const float v0 = fmaxf(acc0[t][0] + bv.x, 0.f);
      const float v1 = fmaxf(acc0[t][1] + bv.y, 0.f);
      const float v2 = fmaxf(acc0[t][2] + bv.z, 0.f);
      const float v3 = fmaxf(acc0[t][3] + bv.w, 0.f);
      uint2 pk;
      pk.x = (unsigned)f2bf(v0) | ((unsigned)f2bf(v1) << 16);
      pk.y = (unsigned)f2bf(v2) | ((unsigned)f2bf(v3) << 16);
      *(uint2*)&xbf[(size_t)(n0 + col) * HID + t * 16 + quad * 4] = pk;
    }
    if (has1) {
      const float v0 = fmaxf(acc1[t][0] + bv.x, 0.f);
      const float v1 = fmaxf(acc1[t][1] + bv.y, 0.f);
      const float v2 = fmaxf(acc1[t][2] + bv.z, 0.f);
      const float v3 = fmaxf(acc1[t][3] + bv.w, 0.f);
      uint2 pk;
      pk.x = (unsigned)f2bf(v0) | ((unsigned)f2bf(v1) << 16);
      pk.y = (unsigned)f2bf(v2) | ((unsigned)f2bf(v3) << 16);
      *(uint2*)&xbf[(size_t)(n1 + col) * HID + t * 16 + quad * 4] = pk;
    }
  }
}

// h = x@W + b (bf16 store); s_src/s_dst per head. TWO tiles per wave.
__device__ inline void proj_work(int pair, int lane,
                                 const unsigned short* __restrict__ xbf,
                                 const unsigned short* __restrict__ wfh,
                                 const unsigned short* __restrict__ wfl,
                                 const float* __restrict__ b,
                                 const float* __restrict__ asrc,
                                 const float* __restrict__ adst,
                                 unsigned short* __restrict__ hbf,
                                 float* __restrict__ ssrc,
                                 float* __restrict__ sdst) {
  const int col = lane & 15, quad = lane >> 4;
  const int tile0 = pair * 2;
  const int tile1 = tile0 + 1;
  const bool has1 = (tile1 < NN / 16);
  const int n0 = tile0 * 16, n1 = tile1 * 16;
  f32x4 acc0[8], acc1[8];
#pragma unroll
  for (int t = 0; t < 8; ++t) {
    acc0[t] = (f32x4){0.f, 0.f, 0.f, 0.f};
    acc1[t] = (f32x4){0.f, 0.f, 0.f, 0.f};
  }
  const unsigned short* brow0 = xbf + (size_t)(n0 + col) * HID + quad * 8;
  const unsigned short* brow1 = xbf + (size_t)((has1 ? n1 : n0) + col) * HID + quad * 8;
  short8 B0[4], B1[4];
#pragma unroll
  for (int c = 0; c < 4; ++c) {
    B0[c] = *(const short8*)(brow0 + c * 32);
    B1[c] = *(const short8*)(brow1 + c * 32);
  }
#pragma unroll
  for (int c = 0; c < 4; ++c) {
#pragma unroll
    for (int t = 0; t < 8; ++t) {
      const short8 Ah = *(const short8*)(wfh + ((size_t)(c * 8 + t) * 64 + lane) * 8);
      const short8 Al = *(const short8*)(wfl + ((size_t)(c * 8 + t) * 64 + lane) * 8);
      acc0[t] = __builtin_amdgcn_mfma_f32_16x16x32_bf16(Al, B0[c], acc0[t], 0, 0, 0);
      acc0[t] = __builtin_amdgcn_mfma_f32_16x16x32_bf16(Ah, B0[c], acc0[t], 0, 0, 0);
      acc1[t] = __builtin_amdgcn_mfma_f32_16x16x32_bf16(Al, B1[c], acc1[t], 0, 0, 0);
      acc1[t] = __builtin_amdgcn_mfma_f32_16x16x32_bf16(Ah, B1[c], acc1[t], 0, 0, 0);
    }
  }
#pragma unroll
  for (int t = 0; t < 8; ++t) {
    const float4 bv = *(const float4*)(b + t * 16 + quad * 4);
    const float4 av = *(const float4*)(asrc + t * 16 + quad * 4);
    const float4 dv = *(const float4*)(adst + t * 16 + quad * 4);
#pragma unroll
    for (int p = 0; p < 2; ++p) {
      if (p == 1 && !has1) break;
      const f32x4& a = p ? acc1[t] : acc0[t];
      const int nb_ = p ? n1 : n0;
      const float v0 = a[0] + bv.x;
      const float v1 = a[1] + bv.y;
      const float v2 = a[2] + bv.z;
      const float v3 = a[3] + bv.w;
      uint2 pk;
      pk.x = (unsigned)f2bf(v0) | ((unsigned)f2bf(v1) << 16);
      pk.y = (unsigned)f2bf(v2) | ((unsigned)f2bf(v3) << 16);
      *(uint2*)&hbf[(size_t)(nb_ + col) * HID + t * 16 + quad * 4] = pk;
      float ps = v0 * av.x + v1 * av.y + v2 * av.z + v3 * av.w;
      float pd = v0 * dv.x + v1 * dv.y + v2 * dv.z + v3 * dv.w;
      ps += __shfl_xor(ps, 16); ps += __shfl_xor(ps, 32);
      pd += __shfl_xor(pd, 16); pd += __shfl_xor(pd, 32);
      if (quad == 0) ssrc[(size_t)(nb_ + col) * HH + t] = ps;
      if (quad == 1) sdst[(size_t)(nb_ + col) * HH + t] = pd;
    }
  }
}

// Fused pca -> layer-0 projection. proj0 reads only the 32 xbf rows this same
// wave just wrote: drain own stores (vmcnt 0), rows are L1-hot on reload.
// No grid-wide ordering needed (pattern correctness-proven in R2).
__global__ __launch_bounds__(64) void pca_proj0_mfma(
    const float* __restrict__ feat,
    const unsigned short* __restrict__ pwh, const unsigned short* __restrict__ pwl,
    const unsigned short* __restrict__ w0h, const unsigned short* __restrict__ w0l,
    const float* __restrict__ pca_b, const float* __restrict__ b0,
    const float* __restrict__ asrc0, const float* __restrict__ adst0,
    unsigned short* __restrict__ xbf, unsigned short* __restrict__ hbf,
    float* __restrict__ ssrc, float* __restrict__ sdst) {
  const int lane = threadIdx.x;
  const int pair = blockIdx.x;
  pca_work(pair, lane, feat, pwh, pwl, pca_b, xbf);
  asm volatile("s_waitcnt vmcnt(0)" ::: "memory");
  proj_work(pair, lane, xbf, w0h, w0l, b0, asrc0, adst0, hbf, ssrc, sdst);
}

// Standalone layer-1 projection.
__global__ __launch_bounds__(64) void proj_mfma(
    const unsigned short* __restrict__ xbf, const unsigned short* __restrict__ wfh,
    const unsigned short* __restrict__ wfl, const float* __restrict__ b,
    const float* __restrict__ asrc, const float* __restrict__ adst,
    unsigned short* __restrict__ hbf, float* __restrict__ ssrc,
    float* __restrict__ sdst) {
  proj_work(blockIdx.x, threadIdx.x, xbf, wfh, wfl, b, asrc, adst, hbf, ssrc, sdst);
}

// attn body: one wave handles a PAIR of nodes per iteration (2-node ILP:
// ~36 outstanding loads issued before either softmax chain). 2-node is the
// VGPR sweet spot (4-node regressed: compiler sank gathers below softmax).
template <bool LAST>
__device__ inline void attn_body(
    const int* __restrict__ nb, const unsigned int* __restrict__ hbf,
    const float* __restrict__ ssrc, const float* __restrict__ sdst,
    void* __restrict__ xout, int lane, int wid, int nwaves) {
  for (int base = wid * 2; base < NN; base += nwaves * 2) {
    const int nA = base, nB = base + 1;
    // lanes 0..15 load nb[nA], lanes 16..31 load nb[nB]
    int nbv = 0;
    if (lane < KK) nbv = nb[(size_t)nA * KK + lane];
    else if (lane < 2 * KK) nbv = nb[(size_t)nB * KK + (lane - KK)];
    unsigned int uA[KK], uB[KK];
#pragma unroll
    for (int k = 0; k < KK; ++k) {
      const int rA = __shfl(nbv, k);
      uA[k] = hbf[(size_t)rA * (HID / 2) + lane];
    }
#pragma unroll
    for (int k = 0; k < KK; ++k) {
      const int rB = __shfl(nbv, KK + k);
      uB[k] = hbf[(size_t)rB * (HID / 2) + lane];
    }
    const int h = lane & 7, k0 = lane >> 3;           // lane = k0*8 + h
    const int rA0 = __shfl(nbv, k0), rA1 = __shfl(nbv, k0 + 8);
    const int rB0 = __shfl(nbv, KK + k0), rB1 = __shfl(nbv, KK + k0 + 8);
    const float ssA = ssrc[(size_t)nA * HH + h];
    const float ssB = ssrc[(size_t)nB * HH + h];
    float eA0 = ssA + sdst[(size_t)rA0 * HH + h];
    float eA1 = ssA + sdst[(size_t)rA1 * HH + h];
    float eB0 = ssB + sdst[(size_t)rB0 * HH + h];
    float eB1 = ssB + sdst[(size_t)rB1 * HH + h];
    eA0 = eA0 > 0.f ? eA0 : 0.2f * eA0;
    eA1 = eA1 > 0.f ? eA1 : 0.2f * eA1;
    eB0 = eB0 > 0.f ? eB0 : 0.2f * eB0;
    eB1 = eB1 > 0.f ? eB1 : 0.2f * eB1;
    float mA = fmaxf(eA0, eA1), mB = fmaxf(eB0, eB1);
    mA = fmaxf(mA, __shfl_xor(mA, 8));  mB = fmaxf(mB, __shfl_xor(mB, 8));
    mA = fmaxf(mA, __shfl_xor(mA, 16)); mB = fmaxf(mB, __shfl_xor(mB, 16));
    mA = fmaxf(mA, __shfl_xor(mA, 32)); mB = fmaxf(mB, __shfl_xor(mB, 32));
    float pA0 = __expf(eA0 - mA), pA1 = __expf(eA1 - mA);
    float pB0 = __expf(eB0 - mB), pB1 = __expf(eB1 - mB);
    float sA = pA0 + pA1, sB = pB0 + pB1;
    sA += __shfl_xor(sA, 8);  sB += __shfl_xor(sB, 8);
    sA += __shfl_xor(sA, 16); sB += __shfl_xor(sB, 16);
    sA += __shfl_xor(sA, 32); sB += __shfl_xor(sB, 32);
    const float invA = 1.f / sA, invB = 1.f / sB;
    pA0 *= invA; pA1 *= invA; pB0 *= invB; pB1 *= invB;
    const int head = lane >> 3;                       // cols 2*lane, 2*lane+1
    float aA0 = 0.f, aA1 = 0.f, aB0 = 0.f, aB1 = 0.f;
#pragma unroll
    for (int k = 0; k < KK; ++k) {
      const float selA = (k < 8) ? pA0 : pA1;
      const float selB = (k < 8) ? pB0 : pB1;
      const float wA = __shfl(selA, ((k & 7) << 3) + head);
      const float wB = __shfl(selB, ((k & 7) << 3) + head);
      aA0 = fmaf(wA, __uint_as_float(uA[k] << 16), aA0);
      aA1 = fmaf(wA, __uint_as_float(uA[k] & 0xffff0000u), aA1);
      aB0 = fmaf(wB, __uint_as_float(uB[k] << 16), aB0);
      aB1 = fmaf(wB, __uint_as_float(uB[k] & 0xffff0000u), aB1);
    }
    const float oA0 = aA0 > 0.f ? aA0 : __expf(aA0) - 1.f;
    const float oA1 = aA1 > 0.f ? aA1 : __expf(aA1) - 1.f;
    const float oB0 = aB0 > 0.f ? aB0 : __expf(aB0) - 1.f;
    const float oB1 = aB1 > 0.f ? aB1 : __expf(aB1) - 1.f;
    if (LAST) {
      *(float2*)((float*)xout + (size_t)nA * HID + 2 * lane) = make_float2(oA0, oA1);
      *(float2*)((float*)xout + (size_t)nB * HID + 2 * lane) = make_float2(oB0, oB1);
    } else {
      ((unsigned int*)xout)[(size_t)nA * (HID / 2) + lane] =
          (unsigned)f2bf(oA0) | ((unsigned)f2bf(oA1) << 16);
      ((unsigned int*)xout)[(size_t)nB * (HID / 2) + lane] =
          (unsigned)f2bf(oB0) | ((unsigned)f2bf(oB1) << 16);
    }
  }
}

__global__ __launch_bounds__(256) void attn0_kernel(
    const int* __restrict__ nb, const unsigned int* __restrict__ hbf,
    const float* __restrict__ ssrc, const float* __restrict__ sdst,
    unsigned short* __restrict__ xbf) {
  const int lane = threadIdx.x & 63;
  const int wid = (blockIdx.x << 2) + (threadIdx.x >> 6);
  attn_body<false>(nb, hbf, ssrc, sdst, (void*)xbf, lane, wid, gridDim.x << 2);
}

__global__ __launch_bounds__(256) void attn1_kernel(
    const int* __restrict__ nb, const unsigned int* __restrict__ hbf,
    const float* __restrict__ ssrc, const float* __restrict__ sdst,
    float* __restrict__ out) {
  const int lane = threadIdx.x & 63;
  const int wid = (blockIdx.x << 2) + (threadIdx.x >> 6);
  attn_body<true>(nb, hbf, ssrc, sdst, (void*)out, lane, wid, gridDim.x << 2);
}

extern "C" void kernel_launch(void* const* d_in, const int* in_sizes, int n_in,
                              void* d_out, int out_size, void* d_ws, size_t ws_size,
                              hipStream_t stream) {
  const float* feature = (const float*)d_in[0];
  const int*   nb      = (const int*)d_in[1];
  const float* pca_w   = (const float*)d_in[2];
  const float* pca_b   = (const float*)d_in[3];
  const float* Ws      = (const float*)d_in[4];
  const float* bs      = (const float*)d_in[5];
  const float* a_src   = (const float*)d_in[6];
  const float* a_dst   = (const float*)d_in[7];
  float* out = (float*)d_out;

  unsigned short* xbf = (unsigned short*)d_ws;                 // [N,128] bf16
  unsigned short* hbf = xbf + (size_t)NN * HID;                // [N,128] bf16
  float* ssrc = (float*)(hbf + (size_t)NN * HID);              // [N,8]
  float* sdst = ssrc + (size_t)NN * HH;                        // [N,8]
  unsigned short* frags = (unsigned short*)(sdst + (size_t)NN * HH); // 106496 shorts

  const int ntile2 = (NN / 16 + 1) / 2;   // 1563 blocks, 2 tiles/wave
  prep_kernel<<<208, 256, 0, stream>>>(pca_w, Ws, frags);
  // Fused: x0 = relu(feat@pca_w+b); h0 = x0@W0+b0; s_src/s_dst.
  pca_proj0_mfma<<<ntile2, 64, 0, stream>>>(
      feature, frags, frags + 20480, frags + 40960, frags + 40960 + 16384,
      pca_b, bs, a_src, a_dst, xbf, hbf, ssrc, sdst);
  attn0_kernel<<<2048, 256, 0, stream>>>(nb, (const unsigned int*)hbf,
                                         ssrc, sdst, xbf);
  const unsigned short* w1 = frags + 40960 + 32768;
  proj_mfma<<<ntile2, 64, 0, stream>>>(
      xbf, w1, w1 + 16384, bs + HID, a_src + HID, a_dst + HID, hbf, ssrc, sdst);
  attn1_kernel<<<2048, 256, 0, stream>>>(nb, (const unsigned int*)hbf,
                                         ssrc, sdst, out);
}

// Round 4
// 216.470 us; speedup vs baseline: 4.8440x; 1.0413x over previous
//
#include <hip/hip_runtime.h>
#include <math.h>

#define NN 50000
#define KK 16
#define FIN 140
#define HH 8
#define HID 128

typedef __attribute__((ext_vector_type(8))) short short8;   // 8 bf16 = 4 VGPRs
typedef __attribute__((ext_vector_type(4))) float f32x4;    // MFMA acc

__device__ inline unsigned short f2bf(float f) {            // RNE fp32->bf16
  unsigned int u = __float_as_uint(f);
  return (unsigned short)((u + 0x7fffu + ((u >> 16) & 1u)) >> 16);
}
__device__ inline float bf2f(unsigned short h) {
  return __uint_as_float(((unsigned int)h) << 16);
}

// Build W^T A-operand fragment tables (hi/lo bf16 split) for pca_w and both Ws.
__global__ __launch_bounds__(256) void prep_kernel(
    const float* __restrict__ pca_w, const float* __restrict__ Ws,
    unsigned short* __restrict__ frags) {
  const int gid = blockIdx.x * 256 + threadIdx.x;   // 208*256 = 53248 exact
  const float* W; int K; unsigned short *dh, *dl; int tid;
  if (gid < 20480)      { W = pca_w;          K = FIN; dh = frags;                 dl = dh + 20480; tid = gid; }
  else if (gid < 36864) { W = Ws;             K = HID; dh = frags + 40960;         dl = dh + 16384; tid = gid - 20480; }
  else                  { W = Ws + HID * HID; K = HID; dh = frags + 40960 + 32768; dl = dh + 16384; tid = gid - 36864; }
  const int j = tid & 7, L = (tid >> 3) & 63, ct = tid >> 9, t = ct & 7, c = ct >> 3;
  const int k = c * 32 + (L >> 4) * 8 + j;
  const int col = t * 16 + (L & 15);
  const float v = (k < K) ? W[(size_t)k * HID + col] : 0.f;
  const unsigned short h = f2bf(v);
  dh[tid] = h;
  dl[tid] = f2bf(v - bf2f(h));
}

// x = relu(feature @ pca_w + b) -> bf16. ONE 16-node tile per wave (R4: was 2;
// 1563 waves @ VGPR=168 was 7.6% occupancy, latency-bound. 3125 waves at ~half
// the VGPR doubles TLP; frag L2 re-stream doubles but is overlapped).
__global__ __launch_bounds__(64) void pca_mfma(
    const float* __restrict__ feat, const unsigned short* __restrict__ wfh,
    const unsigned short* __restrict__ wfl, const float* __restrict__ b,
    unsigned short* __restrict__ xbf) {
  const int lane = threadIdx.x;
  const int col = lane & 15, quad = lane >> 4;
  const int n0 = blockIdx.x * 16;                 // grid = 3125 exact
  f32x4 acc[8];
#pragma unroll
  for (int t = 0; t < 8; ++t) acc[t] = (f32x4){0.f, 0.f, 0.f, 0.f};
  const float* brow = feat + (size_t)(n0 + col) * FIN + quad * 8;
#pragma unroll
  for (int c = 0; c < 5; ++c) {
    float4 a0, a1;
    if (c < 4) {
      a0 = *(const float4*)(brow + c * 32);
      a1 = *(const float4*)(brow + c * 32 + 4);
    } else {  // chunk 4: k = 128 + quad*8 + j, valid only k < 140
      a0 = make_float4(0.f, 0.f, 0.f, 0.f); a1 = a0;
      if (quad == 0) {
        a0 = *(const float4*)(brow + 128); a1 = *(const float4*)(brow + 132);
      } else if (quad == 1) {
        a0 = *(const float4*)(brow + 128);
      }
    }
    short8 B0;
    B0[0] = (short)f2bf(a0.x); B0[1] = (short)f2bf(a0.y);
    B0[2] = (short)f2bf(a0.z); B0[3] = (short)f2bf(a0.w);
    B0[4] = (short)f2bf(a1.x); B0[5] = (short)f2bf(a1.y);
    B0[6] = (short)f2bf(a1.z); B0[7] = (short)f2bf(a1.w);
#pragma unroll
    for (int t = 0; t < 8; ++t) {
      const short8 Ah = *(const short8*)(wfh + ((size_t)(c * 8 + t) * 64 + lane) * 8);
      const short8 Al = *(const short8*)(wfl + ((size_t)(c * 8 + t) * 64 + lane) * 8);
      acc[t] = __builtin_amdgcn_mfma_f32_16x16x32_bf16(Al, B0, acc[t], 0, 0, 0);
      acc[t] = __builtin_amdgcn_mfma_f32_16x16x32_bf16(Ah, B0, acc[t], 0, 0, 0);
    }
  }
#pragma unroll
  for (int t = 0; t < 8; ++t) {
    const float4 bv = *(const float4*)(b + t * 16 + quad * 4);
    const float v0 = fmaxf(acc[t][0] + bv.x, 0.f);
    const float v1 = fmaxf(acc[t][1] + bv.y, 0.f);
    const float v2 = fmaxf(acc[t][2] + bv.z, 0.f);
    const float v3 = fmaxf(acc[t][3] + bv.w, 0.f);
    uint2 pk;
    pk.x = (unsigned)f2bf(v0) | ((unsigned)f2bf(v1) << 16);
    pk.y = (unsigned)f2bf(v2) | ((unsigned)f2bf(v3) << 16);
    *(uint2*)&xbf[(size_t)(n0 + col) * HID + t * 16 + quad * 4] = pk;
  }
}

// h = x@W + b (bf16 store); s_src/s_dst per head. ONE tile per wave.
__global__ __launch_bounds__(64) void proj_mfma(
    const unsigned short* __restrict__ xbf, const unsigned short* __restrict__ wfh,
    const unsigned short* __restrict__ wfl, const float* __restrict__ b,
    const float* __restrict__ asrc, const float* __restrict__ adst,
    unsigned short* __restrict__ hbf, float* __restrict__ ssrc,
    float* __restrict__ sdst) {
  const int lane = threadIdx.x;
  const int col = lane & 15, quad = lane >> 4;
  const int n0 = blockIdx.x * 16;                 // grid = 3125 exact
  f32x4 acc[8];
#pragma unroll
  for (int t = 0; t < 8; ++t) acc[t] = (f32x4){0.f, 0.f, 0.f, 0.f};
  const unsigned short* brow = xbf + (size_t)(n0 + col) * HID + quad * 8;
  short8 B0[4];
#pragma unroll
  for (int c = 0; c < 4; ++c) B0[c] = *(const short8*)(brow + c * 32);
#pragma unroll
  for (int c = 0; c < 4; ++c) {
#pragma unroll
    for (int t = 0; t < 8; ++t) {
      const short8 Ah = *(const short8*)(wfh + ((size_t)(c * 8 + t) * 64 + lane) * 8);
      const short8 Al = *(const short8*)(wfl + ((size_t)(c * 8 + t) * 64 + lane) * 8);
      acc[t] = __builtin_amdgcn_mfma_f32_16x16x32_bf16(Al, B0[c], acc[t], 0, 0, 0);
      acc[t] = __builtin_amdgcn_mfma_f32_16x16x32_bf16(Ah, B0[c], acc[t], 0, 0, 0);
    }
  }
  // lane holds node n0+col, out-cols t*16+quad*4+r (head == t)
#pragma unroll
  for (int t = 0; t < 8; ++t) {
    const float4 bv = *(const float4*)(b + t * 16 + quad * 4);
    const float4 av = *(const float4*)(asrc + t * 16 + quad * 4);
    const float4 dv = *(const float4*)(adst + t * 16 + quad * 4);
    const float v0 = acc[t][0] + bv.x;
    const float v1 = acc[t][1] + bv.y;
    const float v2 = acc[t][2] + bv.z;
    const float v3 = acc[t][3] + bv.w;
    uint2 pk;
    pk.x = (unsigned)f2bf(v0) | ((unsigned)f2bf(v1) << 16);
    pk.y = (unsigned)f2bf(v2) | ((unsigned)f2bf(v3) << 16);
    *(uint2*)&hbf[(size_t)(n0 + col) * HID + t * 16 + quad * 4] = pk;
    float ps = v0 * av.x + v1 * av.y + v2 * av.z + v3 * av.w;
    float pd = v0 * dv.x + v1 * dv.y + v2 * dv.z + v3 * dv.w;
    ps += __shfl_xor(ps, 16); ps += __shfl_xor(ps, 32);
    pd += __shfl_xor(pd, 16); pd += __shfl_xor(pd, 32);
    if (quad == 0) ssrc[(size_t)(n0 + col) * HH + t] = ps;
    if (quad == 1) sdst[(size_t)(n0 + col) * HH + t] = pd;
  }
}

// attn body: one wave handles a PAIR of nodes per iteration (2-node ILP:
// ~36 outstanding loads issued before either softmax chain). 2-node is the
// VGPR sweet spot (4-node regressed: compiler sank gathers below softmax).
template <bool LAST>
__device__ inline void attn_body(
    const int* __restrict__ nb, const unsigned int* __restrict__ hbf,
    const float* __restrict__ ssrc, const float* __restrict__ sdst,
    void* __restrict__ xout, int lane, int wid, int nwaves) {
  for (int base = wid * 2; base < NN; base += nwaves * 2) {
    const int nA = base, nB = base + 1;
    // lanes 0..15 load nb[nA], lanes 16..31 load nb[nB]
    int nbv = 0;
    if (lane < KK) nbv = nb[(size_t)nA * KK + lane];
    else if (lane < 2 * KK) nbv = nb[(size_t)nB * KK + (lane - KK)];
    unsigned int uA[KK], uB[KK];
#pragma unroll
    for (int k = 0; k < KK; ++k) {
      const int rA = __shfl(nbv, k);
      uA[k] = hbf[(size_t)rA * (HID / 2) + lane];
    }
#pragma unroll
    for (int k = 0; k < KK; ++k) {
      const int rB = __shfl(nbv, KK + k);
      uB[k] = hbf[(size_t)rB * (HID / 2) + lane];
    }
    const int h = lane & 7, k0 = lane >> 3;           // lane = k0*8 + h
    const int rA0 = __shfl(nbv, k0), rA1 = __shfl(nbv, k0 + 8);
    const int rB0 = __shfl(nbv, KK + k0), rB1 = __shfl(nbv, KK + k0 + 8);
    const float ssA = ssrc[(size_t)nA * HH + h];
    const float ssB = ssrc[(size_t)nB * HH + h];
    float eA0 = ssA + sdst[(size_t)rA0 * HH + h];
    float eA1 = ssA + sdst[(size_t)rA1 * HH + h];
    float eB0 = ssB + sdst[(size_t)rB0 * HH + h];
    float eB1 = ssB + sdst[(size_t)rB1 * HH + h];
    eA0 = eA0 > 0.f ? eA0 : 0.2f * eA0;
    eA1 = eA1 > 0.f ? eA1 : 0.2f * eA1;
    eB0 = eB0 > 0.f ? eB0 : 0.2f * eB0;
    eB1 = eB1 > 0.f ? eB1 : 0.2f * eB1;
    float mA = fmaxf(eA0, eA1), mB = fmaxf(eB0, eB1);
    mA = fmaxf(mA, __shfl_xor(mA, 8));  mB = fmaxf(mB, __shfl_xor(mB, 8));
    mA = fmaxf(mA, __shfl_xor(mA, 16)); mB = fmaxf(mB, __shfl_xor(mB, 16));
    mA = fmaxf(mA, __shfl_xor(mA, 32)); mB = fmaxf(mB, __shfl_xor(mB, 32));
    float pA0 = __expf(eA0 - mA), pA1 = __expf(eA1 - mA);
    float pB0 = __expf(eB0 - mB), pB1 = __expf(eB1 - mB);
    float sA = pA0 + pA1, sB = pB0 + pB1;
    sA += __shfl_xor(sA, 8);  sB += __shfl_xor(sB, 8);
    sA += __shfl_xor(sA, 16); sB += __shfl_xor(sB, 16);
    sA += __shfl_xor(sA, 32); sB += __shfl_xor(sB, 32);
    const float invA = 1.f / sA, invB = 1.f / sB;
    pA0 *= invA; pA1 *= invA; pB0 *= invB; pB1 *= invB;
    const int head = lane >> 3;                       // cols 2*lane, 2*lane+1
    float aA0 = 0.f, aA1 = 0.f, aB0 = 0.f, aB1 = 0.f;
#pragma unroll
    for (int k = 0; k < KK; ++k) {
      const float selA = (k < 8) ? pA0 : pA1;
      const float selB = (k < 8) ? pB0 : pB1;
      const float wA = __shfl(selA, ((k & 7) << 3) + head);
      const float wB = __shfl(selB, ((k & 7) << 3) + head);
      aA0 = fmaf(wA, __uint_as_float(uA[k] << 16), aA0);
      aA1 = fmaf(wA, __uint_as_float(uA[k] & 0xffff0000u), aA1);
      aB0 = fmaf(wB, __uint_as_float(uB[k] << 16), aB0);
      aB1 = fmaf(wB, __uint_as_float(uB[k] & 0xffff0000u), aB1);
    }
    const float oA0 = aA0 > 0.f ? aA0 : __expf(aA0) - 1.f;
    const float oA1 = aA1 > 0.f ? aA1 : __expf(aA1) - 1.f;
    const float oB0 = aB0 > 0.f ? aB0 : __expf(aB0) - 1.f;
    const float oB1 = aB1 > 0.f ? aB1 : __expf(aB1) - 1.f;
    if (LAST) {
      *(float2*)((float*)xout + (size_t)nA * HID + 2 * lane) = make_float2(oA0, oA1);
      *(float2*)((float*)xout + (size_t)nB * HID + 2 * lane) = make_float2(oB0, oB1);
    } else {
      ((unsigned int*)xout)[(size_t)nA * (HID / 2) + lane] =
          (unsigned)f2bf(oA0) | ((unsigned)f2bf(oA1) << 16);
      ((unsigned int*)xout)[(size_t)nB * (HID / 2) + lane] =
          (unsigned)f2bf(oB0) | ((unsigned)f2bf(oB1) << 16);
    }
  }
}

__global__ __launch_bounds__(256) void attn0_kernel(
    const int* __restrict__ nb, const unsigned int* __restrict__ hbf,
    const float* __restrict__ ssrc, const float* __restrict__ sdst,
    unsigned short* __restrict__ xbf) {
  const int lane = threadIdx.x & 63;
  const int wid = (blockIdx.x << 2) + (threadIdx.x >> 6);
  attn_body<false>(nb, hbf, ssrc, sdst, (void*)xbf, lane, wid, gridDim.x << 2);
}

__global__ __launch_bounds__(256) void attn1_kernel(
    const int* __restrict__ nb, const unsigned int* __restrict__ hbf,
    const float* __restrict__ ssrc, const float* __restrict__ sdst,
    float* __restrict__ out) {
  const int lane = threadIdx.x & 63;
  const int wid = (blockIdx.x << 2) + (threadIdx.x >> 6);
  attn_body<true>(nb, hbf, ssrc, sdst, (void*)out, lane, wid, gridDim.x << 2);
}

extern "C" void kernel_launch(void* const* d_in, const int* in_sizes, int n_in,
                              void* d_out, int out_size, void* d_ws, size_t ws_size,
                              hipStream_t stream) {
  const float* feature = (const float*)d_in[0];
  const int*   nb      = (const int*)d_in[1];
  const float* pca_w   = (const float*)d_in[2];
  const float* pca_b   = (const float*)d_in[3];
  const float* Ws      = (const float*)d_in[4];
  const float* bs      = (const float*)d_in[5];
  const float* a_src   = (const float*)d_in[6];
  const float* a_dst   = (const float*)d_in[7];
  float* out = (float*)d_out;

  unsigned short* xbf = (unsigned short*)d_ws;                 // [N,128] bf16
  unsigned short* hbf = xbf + (size_t)NN * HID;                // [N,128] bf16
  float* ssrc = (float*)(hbf + (size_t)NN * HID);              // [N,8]
  float* sdst = ssrc + (size_t)NN * HH;                        // [N,8]
  unsigned short* frags = (unsigned short*)(sdst + (size_t)NN * HH); // 106496 shorts

  const int ntile = NN / 16;              // 3125 tiles, 1 tile/wave
  prep_kernel<<<208, 256, 0, stream>>>(pca_w, Ws, frags);
  pca_mfma<<<ntile, 64, 0, stream>>>(feature, frags, frags + 20480, pca_b, xbf);
  proj_mfma<<<ntile, 64, 0, stream>>>(
      xbf, frags + 40960, frags + 40960 + 16384, bs, a_src, a_dst,
      hbf, ssrc, sdst);
  attn0_kernel<<<2048, 256, 0, stream>>>(nb, (const unsigned int*)hbf,
                                         ssrc, sdst, xbf);
  const unsigned short* w1 = frags + 40960 + 32768;
  proj_mfma<<<ntile, 64, 0, stream>>>(
      xbf, w1, w1 + 16384, bs + HID, a_src + HID, a_dst + HID, hbf, ssrc, sdst);
  attn1_kernel<<<2048, 256, 0, stream>>>(nb, (const unsigned int*)hbf,
                                         ssrc, sdst, out);
}

// Round 5
// 205.603 us; speedup vs baseline: 5.1001x; 1.0529x over previous
//
#include <hip/hip_runtime.h>
#include <math.h>

#define NN 50000
#define KK 16
#define FIN 140
#define HH 8
#define HID 128

typedef __attribute__((ext_vector_type(8))) short short8;   // 8 bf16 = 4 VGPRs
typedef __attribute__((ext_vector_type(4))) float f32x4;    // MFMA acc

__device__ inline unsigned short f2bf(float f) {            // RNE fp32->bf16
  unsigned int u = __float_as_uint(f);
  return (unsigned short)((u + 0x7fffu + ((u >> 16) & 1u)) >> 16);
}
__device__ inline float bf2f(unsigned short h) {
  return __uint_as_float(((unsigned int)h) << 16);
}

// Build W^T A-operand fragment tables (hi/lo bf16 split) for pca_w and both Ws.
__global__ __launch_bounds__(256) void prep_kernel(
    const float* __restrict__ pca_w, const float* __restrict__ Ws,
    unsigned short* __restrict__ frags) {
  const int gid = blockIdx.x * 256 + threadIdx.x;   // 208*256 = 53248 exact
  const float* W; int K; unsigned short *dh, *dl; int tid;
  if (gid < 20480)      { W = pca_w;          K = FIN; dh = frags;                 dl = dh + 20480; tid = gid; }
  else if (gid < 36864) { W = Ws;             K = HID; dh = frags + 40960;         dl = dh + 16384; tid = gid - 20480; }
  else                  { W = Ws + HID * HID; K = HID; dh = frags + 40960 + 32768; dl = dh + 16384; tid = gid - 36864; }
  const int j = tid & 7, L = (tid >> 3) & 63, ct = tid >> 9, t = ct & 7, c = ct >> 3;
  const int k = c * 32 + (L >> 4) * 8 + j;
  const int col = t * 16 + (L & 15);
  const float v = (k < K) ? W[(size_t)k * HID + col] : 0.f;
  const unsigned short h = f2bf(v);
  dh[tid] = h;
  dl[tid] = f2bf(v - bf2f(h));
}

// x = relu(feature @ pca_w + b) -> bf16. ONE 16-node tile per wave.
__global__ __launch_bounds__(64) void pca_mfma(
    const float* __restrict__ feat, const unsigned short* __restrict__ wfh,
    const unsigned short* __restrict__ wfl, const float* __restrict__ b,
    unsigned short* __restrict__ xbf) {
  const int lane = threadIdx.x;
  const int col = lane & 15, quad = lane >> 4;
  const int n0 = blockIdx.x * 16;                 // grid = 3125 exact
  f32x4 acc[8];
#pragma unroll
  for (int t = 0; t < 8; ++t) acc[t] = (f32x4){0.f, 0.f, 0.f, 0.f};
  const float* brow = feat + (size_t)(n0 + col) * FIN + quad * 8;
#pragma unroll
  for (int c = 0; c < 5; ++c) {
    float4 a0, a1;
    if (c < 4) {
      a0 = *(const float4*)(brow + c * 32);
      a1 = *(const float4*)(brow + c * 32 + 4);
    } else {  // chunk 4: k = 128 + quad*8 + j, valid only k < 140
      a0 = make_float4(0.f, 0.f, 0.f, 0.f); a1 = a0;
      if (quad == 0) {
        a0 = *(const float4*)(brow + 128); a1 = *(const float4*)(brow + 132);
      } else if (quad == 1) {
        a0 = *(const float4*)(brow + 128);
      }
    }
    short8 B0;
    B0[0] = (short)f2bf(a0.x); B0[1] = (short)f2bf(a0.y);
    B0[2] = (short)f2bf(a0.z); B0[3] = (short)f2bf(a0.w);
    B0[4] = (short)f2bf(a1.x); B0[5] = (short)f2bf(a1.y);
    B0[6] = (short)f2bf(a1.z); B0[7] = (short)f2bf(a1.w);
#pragma unroll
    for (int t = 0; t < 8; ++t) {
      const short8 Ah = *(const short8*)(wfh + ((size_t)(c * 8 + t) * 64 + lane) * 8);
      const short8 Al = *(const short8*)(wfl + ((size_t)(c * 8 + t) * 64 + lane) * 8);
      acc[t] = __builtin_amdgcn_mfma_f32_16x16x32_bf16(Al, B0, acc[t], 0, 0, 0);
      acc[t] = __builtin_amdgcn_mfma_f32_16x16x32_bf16(Ah, B0, acc[t], 0, 0, 0);
    }
  }
#pragma unroll
  for (int t = 0; t < 8; ++t) {
    const float4 bv = *(const float4*)(b + t * 16 + quad * 4);
    const float v0 = fmaxf(acc[t][0] + bv.x, 0.f);
    const float v1 = fmaxf(acc[t][1] + bv.y, 0.f);
    const float v2 = fmaxf(acc[t][2] + bv.z, 0.f);
    const float v3 = fmaxf(acc[t][3] + bv.w, 0.f);
    uint2 pk;
    pk.x = (unsigned)f2bf(v0) | ((unsigned)f2bf(v1) << 16);
    pk.y = (unsigned)f2bf(v2) | ((unsigned)f2bf(v3) << 16);
    *(uint2*)&xbf[(size_t)(n0 + col) * HID + t * 16 + quad * 4] = pk;
  }
}

// h = x@W + b (bf16 store); s_src/s_dst per head. ONE tile per wave.
__global__ __launch_bounds__(64) void proj_mfma(
    const unsigned short* __restrict__ xbf, const unsigned short* __restrict__ wfh,
    const unsigned short* __restrict__ wfl, const float* __restrict__ b,
    const float* __restrict__ asrc, const float* __restrict__ adst,
    unsigned short* __restrict__ hbf, float* __restrict__ ssrc,
    float* __restrict__ sdst) {
  const int lane = threadIdx.x;
  const int col = lane & 15, quad = lane >> 4;
  const int n0 = blockIdx.x * 16;                 // grid = 3125 exact
  f32x4 acc[8];
#pragma unroll
  for (int t = 0; t < 8; ++t) acc[t] = (f32x4){0.f, 0.f, 0.f, 0.f};
  const unsigned short* brow = xbf + (size_t)(n0 + col) * HID + quad * 8;
  short8 B0[4];
#pragma unroll
  for (int c = 0; c < 4; ++c) B0[c] = *(const short8*)(brow + c * 32);
#pragma unroll
  for (int c = 0; c < 4; ++c) {
#pragma unroll
    for (int t = 0; t < 8; ++t) {
      const short8 Ah = *(const short8*)(wfh + ((size_t)(c * 8 + t) * 64 + lane) * 8);
      const short8 Al = *(const short8*)(wfl + ((size_t)(c * 8 + t) * 64 + lane) * 8);
      acc[t] = __builtin_amdgcn_mfma_f32_16x16x32_bf16(Al, B0[c], acc[t], 0, 0, 0);
      acc[t] = __builtin_amdgcn_mfma_f32_16x16x32_bf16(Ah, B0[c], acc[t], 0, 0, 0);
    }
  }
  // lane holds node n0+col, out-cols t*16+quad*4+r (head == t)
#pragma unroll
  for (int t = 0; t < 8; ++t) {
    const float4 bv = *(const float4*)(b + t * 16 + quad * 4);
    const float4 av = *(const float4*)(asrc + t * 16 + quad * 4);
    const float4 dv = *(const float4*)(adst + t * 16 + quad * 4);
    const float v0 = acc[t][0] + bv.x;
    const float v1 = acc[t][1] + bv.y;
    const float v2 = acc[t][2] + bv.z;
    const float v3 = acc[t][3] + bv.w;
    uint2 pk;
    pk.x = (unsigned)f2bf(v0) | ((unsigned)f2bf(v1) << 16);
    pk.y = (unsigned)f2bf(v2) | ((unsigned)f2bf(v3) << 16);
    *(uint2*)&hbf[(size_t)(n0 + col) * HID + t * 16 + quad * 4] = pk;
    float ps = v0 * av.x + v1 * av.y + v2 * av.z + v3 * av.w;
    float pd = v0 * dv.x + v1 * dv.y + v2 * dv.z + v3 * dv.w;
    ps += __shfl_xor(ps, 16); ps += __shfl_xor(ps, 32);
    pd += __shfl_xor(pd, 16); pd += __shfl_xor(pd, 32);
    if (quad == 0) ssrc[(size_t)(n0 + col) * HH + t] = ps;
    if (quad == 1) sdst[(size_t)(n0 + col) * HH + t] = pd;
  }
}

// attn: ONE pair per wave (R5: was 2 pairs * 3-4 serial loop iterations per
// wave at 8192 waves; 25000 waves with no loop removes the serial latency
// chains and the 8192/25000 tail imbalance; latency hides across waves).
template <bool LAST>
__device__ inline void attn_pair(
    const int* __restrict__ nb, const unsigned int* __restrict__ hbf,
    const float* __restrict__ ssrc, const float* __restrict__ sdst,
    void* __restrict__ xout, int lane, int wid) {
  const int base = wid * 2;
  const int nA = base, nB = base + 1;
  // lanes 0..15 load nb[nA], lanes 16..31 load nb[nB]
  int nbv = 0;
  if (lane < KK) nbv = nb[(size_t)nA * KK + lane];
  else if (lane < 2 * KK) nbv = nb[(size_t)nB * KK + (lane - KK)];
  unsigned int uA[KK], uB[KK];
#pragma unroll
  for (int k = 0; k < KK; ++k) {
    const int rA = __shfl(nbv, k);
    uA[k] = hbf[(size_t)rA * (HID / 2) + lane];
  }
#pragma unroll
  for (int k = 0; k < KK; ++k) {
    const int rB = __shfl(nbv, KK + k);
    uB[k] = hbf[(size_t)rB * (HID / 2) + lane];
  }
  const int h = lane & 7, k0 = lane >> 3;           // lane = k0*8 + h
  const int rA0 = __shfl(nbv, k0), rA1 = __shfl(nbv, k0 + 8);
  const int rB0 = __shfl(nbv, KK + k0), rB1 = __shfl(nbv, KK + k0 + 8);
  const float ssA = ssrc[(size_t)nA * HH + h];
  const float ssB = ssrc[(size_t)nB * HH + h];
  float eA0 = ssA + sdst[(size_t)rA0 * HH + h];
  float eA1 = ssA + sdst[(size_t)rA1 * HH + h];
  float eB0 = ssB + sdst[(size_t)rB0 * HH + h];
  float eB1 = ssB + sdst[(size_t)rB1 * HH + h];
  eA0 = eA0 > 0.f ? eA0 : 0.2f * eA0;
  eA1 = eA1 > 0.f ? eA1 : 0.2f * eA1;
  eB0 = eB0 > 0.f ? eB0 : 0.2f * eB0;
  eB1 = eB1 > 0.f ? eB1 : 0.2f * eB1;
  float mA = fmaxf(eA0, eA1), mB = fmaxf(eB0, eB1);
  mA = fmaxf(mA, __shfl_xor(mA, 8));  mB = fmaxf(mB, __shfl_xor(mB, 8));
  mA = fmaxf(mA, __shfl_xor(mA, 16)); mB = fmaxf(mB, __shfl_xor(mB, 16));
  mA = fmaxf(mA, __shfl_xor(mA, 32)); mB = fmaxf(mB, __shfl_xor(mB, 32));
  float pA0 = __expf(eA0 - mA), pA1 = __expf(eA1 - mA);
  float pB0 = __expf(eB0 - mB), pB1 = __expf(eB1 - mB);
  float sA = pA0 + pA1, sB = pB0 + pB1;
  sA += __shfl_xor(sA, 8);  sB += __shfl_xor(sB, 8);
  sA += __shfl_xor(sA, 16); sB += __shfl_xor(sB, 16);
  sA += __shfl_xor(sA, 32); sB += __shfl_xor(sB, 32);
  const float invA = 1.f / sA, invB = 1.f / sB;
  pA0 *= invA; pA1 *= invA; pB0 *= invB; pB1 *= invB;
  const int head = lane >> 3;                       // cols 2*lane, 2*lane+1
  float aA0 = 0.f, aA1 = 0.f, aB0 = 0.f, aB1 = 0.f;
#pragma unroll
  for (int k = 0; k < KK; ++k) {
    const float selA = (k < 8) ? pA0 : pA1;
    const float selB = (k < 8) ? pB0 : pB1;
    const float wA = __shfl(selA, ((k & 7) << 3) + head);
    const float wB = __shfl(selB, ((k & 7) << 3) + head);
    aA0 = fmaf(wA, __uint_as_float(uA[k] << 16), aA0);
    aA1 = fmaf(wA, __uint_as_float(uA[k] & 0xffff0000u), aA1);
    aB0 = fmaf(wB, __uint_as_float(uB[k] << 16), aB0);
    aB1 = fmaf(wB, __uint_as_float(uB[k] & 0xffff0000u), aB1);
  }
  const float oA0 = aA0 > 0.f ? aA0 : __expf(aA0) - 1.f;
  const float oA1 = aA1 > 0.f ? aA1 : __expf(aA1) - 1.f;
  const float oB0 = aB0 > 0.f ? aB0 : __expf(aB0) - 1.f;
  const float oB1 = aB1 > 0.f ? aB1 : __expf(aB1) - 1.f;
  if (LAST) {
    *(float2*)((float*)xout + (size_t)nA * HID + 2 * lane) = make_float2(oA0, oA1);
    *(float2*)((float*)xout + (size_t)nB * HID + 2 * lane) = make_float2(oB0, oB1);
  } else {
    ((unsigned int*)xout)[(size_t)nA * (HID / 2) + lane] =
        (unsigned)f2bf(oA0) | ((unsigned)f2bf(oA1) << 16);
    ((unsigned int*)xout)[(size_t)nB * (HID / 2) + lane] =
        (unsigned)f2bf(oB0) | ((unsigned)f2bf(oB1) << 16);
  }
}

__global__ __launch_bounds__(256) void attn0_kernel(
    const int* __restrict__ nb, const unsigned int* __restrict__ hbf,
    const float* __restrict__ ssrc, const float* __restrict__ sdst,
    unsigned short* __restrict__ xbf) {
  const int lane = threadIdx.x & 63;
  const int wid = (blockIdx.x << 2) + (threadIdx.x >> 6);
  if (wid >= NN / 2) return;                       // 6250*4 = 25000 exact
  attn_pair<false>(nb, hbf, ssrc, sdst, (void*)xbf, lane, wid);
}

__global__ __launch_bounds__(256) void attn1_kernel(
    const int* __restrict__ nb, const unsigned int* __restrict__ hbf,
    const float* __restrict__ ssrc, const float* __restrict__ sdst,
    float* __restrict__ out) {
  const int lane = threadIdx.x & 63;
  const int wid = (blockIdx.x << 2) + (threadIdx.x >> 6);
  if (wid >= NN / 2) return;
  attn_pair<true>(nb, hbf, ssrc, sdst, (void*)out, lane, wid);
}

extern "C" void kernel_launch(void* const* d_in, const int* in_sizes, int n_in,
                              void* d_out, int out_size, void* d_ws, size_t ws_size,
                              hipStream_t stream) {
  const float* feature = (const float*)d_in[0];
  const int*   nb      = (const int*)d_in[1];
  const float* pca_w   = (const float*)d_in[2];
  const float* pca_b   = (const float*)d_in[3];
  const float* Ws      = (const float*)d_in[4];
  const float* bs      = (const float*)d_in[5];
  const float* a_src   = (const float*)d_in[6];
  const float* a_dst   = (const float*)d_in[7];
  float* out = (float*)d_out;

  unsigned short* xbf = (unsigned short*)d_ws;                 // [N,128] bf16
  unsigned short* hbf = xbf + (size_t)NN * HID;                // [N,128] bf16
  float* ssrc = (float*)(hbf + (size_t)NN * HID);              // [N,8]
  float* sdst = ssrc + (size_t)NN * HH;                        // [N,8]
  unsigned short* frags = (unsigned short*)(sdst + (size_t)NN * HH); // 106496 shorts

  const int ntile = NN / 16;              // 3125 tiles, 1 tile/wave
  const int nattn = (NN / 2 + 3) / 4;     // 6250 blocks, 1 pair/wave
  prep_kernel<<<208, 256, 0, stream>>>(pca_w, Ws, frags);
  pca_mfma<<<ntile, 64, 0, stream>>>(feature, frags, frags + 20480, pca_b, xbf);
  proj_mfma<<<ntile, 64, 0, stream>>>(
      xbf, frags + 40960, frags + 40960 + 16384, bs, a_src, a_dst,
      hbf, ssrc, sdst);
  attn0_kernel<<<nattn, 256, 0, stream>>>(nb, (const unsigned int*)hbf,
                                          ssrc, sdst, xbf);
  const unsigned short* w1 = frags + 40960 + 32768;
  proj_mfma<<<ntile, 64, 0, stream>>>(
      xbf, w1, w1 + 16384, bs + HID, a_src + HID, a_dst + HID, hbf, ssrc, sdst);
  attn1_kernel<<<nattn, 256, 0, stream>>>(nb, (const unsigned int*)hbf,
                                          ssrc, sdst, out);
}